// Round 9
// baseline (2635.765 us; speedup 1.0000x reference)
//
#include <hip/hip_runtime.h>
#include <hip/hip_bf16.h>

typedef __hip_bfloat16 bf16_t;

#define N_NODES 10000
#define N_EDGES 100000
#define N_BONDS 1000

__device__ __forceinline__ float bf2f(bf16_t v){ return __bfloat162float(v); }
__device__ __forceinline__ bf16_t f2bf(float v){ return __float2bfloat16(v); }
__device__ __forceinline__ int iabs(int x){ return x<0?-x:x; }

__device__ __forceinline__ void stout(void* out, size_t idx, float v, bool f32o){
  if (f32o) ((float*)out)[idx]=v;
  else      ((bf16_t*)out)[idx]=f2bf(v);
}

// =====================================================================
// Dtype detection: num_neighbors == 10.0 always. bf16 -> u16[0]==0x4120.
// =====================================================================
__global__ void detect_k(const unsigned short* nnb_raw, int* flag){
  *flag = (nnb_raw[0]==0x4120) ? 0 : 1;
}

struct CvtArgs {
  const void* src[19];
  float* dst[19];
  int n[19];
};

__global__ __launch_bounds__(256) void convert_k(CvtArgs a, const int* flag){
  bool f32 = (*flag)!=0;
  int tid = blockIdx.x*256+threadIdx.x;
  int nth = gridDim.x*256;
  for(int t=0;t<19;++t){
    int n=a.n[t];
    float* d=a.dst[t];
    if (f32){
      const float* s=(const float*)a.src[t];
      for(int i=tid;i<n;i+=nth) d[i]=s[i];
    } else {
      const bf16_t* s=(const bf16_t*)a.src[t];
      for(int i=tid;i<n;i+=nth) d[i]=bf2f(s[i]);
    }
  }
}

// =====================================================================
// CSR build: edges sorted by destination node
// =====================================================================
__global__ __launch_bounds__(256) void csr_count_k(const int* __restrict__ edst, int* __restrict__ cnt){
  int e=blockIdx.x*256+threadIdx.x; if(e>=N_EDGES) return;
  atomicAdd(&cnt[edst[e]],1);
}

__global__ __launch_bounds__(256) void csr_scan_k(const int* __restrict__ cnt,
    int* __restrict__ rowptr, int* __restrict__ pos){
  __shared__ int ssum[256];
  int t=threadIdx.x;
  int base=t*40;
  int s=0;
  for(int i=0;i<40;++i){ int idx=base+i; s += (idx<N_NODES)? cnt[idx]:0; }
  ssum[t]=s; __syncthreads();
  if(t==0){ int run=0; for(int i=0;i<256;++i){ int v=ssum[i]; ssum[i]=run; run+=v; } }
  __syncthreads();
  int run=ssum[t];
  for(int i=0;i<40;++i){
    int idx=base+i;
    if(idx<N_NODES){ rowptr[idx]=run; pos[idx]=run; run+=cnt[idx]; }
  }
  if(t==255) rowptr[N_NODES]=run;
}

__global__ __launch_bounds__(256) void csr_scatter_k(const int* __restrict__ edst,
    int* __restrict__ pos, int* __restrict__ sorted){
  int e=blockIdx.x*256+threadIdx.x; if(e>=N_EDGES) return;
  int p=atomicAdd(&pos[edst[e]],1);
  sorted[p]=e;
}

// =====================================================================
// CG tables (device, double precision, exact replica of reference)
// =====================================================================
__device__ __forceinline__ double dfact(int n){
  const double F[11]={1.,1.,2.,6.,24.,120.,720.,5040.,40320.,362880.,3628800.};
  return F[n];
}

__device__ double cgc_d(int j1,int m1,int j2,int m2,int j3,int m3){
  if (m1+m2!=m3) return 0.0;
  double pre = sqrt((double)(2*j3+1)*dfact(j3+j1-j2)*dfact(j3-j1+j2)*dfact(j1+j2-j3)/dfact(j1+j2+j3+1));
  pre *= sqrt(dfact(j3+m3)*dfact(j3-m3)*dfact(j1-m1)*dfact(j1+m1)*dfact(j2-m2)*dfact(j2+m2));
  int k0 = max(0, max(j2-j3-m1, j1-j3+m2));
  int k1 = min(j1+j2-j3, min(j1-m1, j2+m2));
  double s=0.0;
  for(int k=k0;k<=k1;++k)
    s += ((k&1)?-1.0:1.0)/(dfact(k)*dfact(j1+j2-j3-k)*dfact(j1-m1-k)*dfact(j2+m2-k)*dfact(j3-j2+m1+k)*dfact(j3-j1-m2+k));
  return pre*s;
}

__device__ void c2r_d(int l,int a,int m,double&re,double&im){
  re=0.0; im=0.0;
  const double r2 = 0.7071067811865475244;
  int mu = a-l;
  if (mu==0){ if (m==l) re=1.0; return; }
  if (mu>0){
    if (m==l+mu) re = (mu&1)? -r2 : r2;
    else if (m==l-mu) re = r2;
  } else {
    int nu=-mu;
    if (m==l-nu) im = r2;
    else if (m==l+nu) im = (nu&1)? r2 : -r2;
  }
}

__global__ __launch_bounds__(128) void cg_init_k(float* cg){
  int b=blockIdx.x;
  int l1=b/9, l2=(b/3)%3, l3=b%3;
  if (l3 < iabs(l1-l2) || l3 > l1+l2) return;
  int n1=2*l1+1,n2=2*l2+1,n3=2*l3+1,n=n1*n2*n3;
  __shared__ double sRe[125], sIm[125];
  __shared__ int sPick;
  int t=threadIdx.x;
  if (t<n){
    int a=t/(n2*n3), bb=(t/n3)%n2, c=t%n3;
    double re=0.0, im=0.0;
    for(int m1=0;m1<n1;++m1){
      double q1r,q1i; c2r_d(l1,a,m1,q1r,q1i);
      if (q1r==0.0 && q1i==0.0) continue;
      for(int m2=0;m2<n2;++m2){
        double q2r,q2i; c2r_d(l2,bb,m2,q2r,q2i);
        if (q2r==0.0 && q2i==0.0) continue;
        int m3=(m1-l1)+(m2-l2)+l3;
        if (m3<0||m3>=n3) continue;
        double q3r,q3i; c2r_d(l3,c,m3,q3r,q3i); q3i=-q3i;
        double C = cgc_d(l1,m1-l1,l2,m2-l2,l3,m3-l3);
        if (C==0.0) continue;
        double ar = q1r*q2r - q1i*q2i;
        double ai = q1r*q2i + q1i*q2r;
        re += (ar*q3r - ai*q3i)*C;
        im += (ar*q3i + ai*q3r)*C;
      }
    }
    sRe[t]=re; sIm[t]=im;
  }
  __syncthreads();
  if (t==0){
    double s1=0.0,s2=0.0;
    for(int i=0;i<n;++i){ s1+=fabs(sRe[i]); s2+=fabs(sIm[i]); }
    sPick = (s1>=s2)?1:0;
  }
  __syncthreads();
  if (t<n) cg[b*125+t] = (float)(sPick? sRe[t] : sIm[t]);
}

// =====================================================================
// Stage A: x1 = tanh(f_in @ W(2x2) / sqrt(2))
// =====================================================================
__global__ __launch_bounds__(256) void nodeA_k(const float* __restrict__ fin,
                                               const float* __restrict__ w,
                                               float* __restrict__ x1){
  int n=blockIdx.x*256+threadIdx.x; if(n>=N_NODES) return;
  float f0=fin[2*n], f1=fin[2*n+1];
  const float r2=0.70710678f;
  x1[2*n]   = tanhf((f0*w[0]+f1*w[2])*r2);
  x1[2*n+1] = tanhf((f0*w[1]+f1*w[3])*r2);
}

// MLP [1,16,16,16] layers 0..2 of fc_apply (relu after each)
__device__ __forceinline__ void mlp16(float e, const float* w, float* h){
  float a[16];
  #pragma unroll
  for(int j=0;j<16;++j) a[j]=fmaxf(e*w[j],0.f);
  float b[16];
  #pragma unroll
  for(int j=0;j<16;++j){
    float s=0.f;
    #pragma unroll
    for(int i=0;i<16;++i) s+=a[i]*w[16+i*16+j];
    b[j]=fmaxf(s*0.25f,0.f);
  }
  #pragma unroll
  for(int j=0;j<16;++j){
    float s=0.f;
    #pragma unroll
    for(int i=0;i<16;++i) s+=b[i]*w[272+i*16+j];
    h[j]=fmaxf(s*0.25f,0.f);
  }
}

__global__ __launch_bounds__(256) void hmlp_k(const float* __restrict__ emb,
    const float* __restrict__ wfc, float* __restrict__ H, int E){
  __shared__ float sw[528];
  for(int t=threadIdx.x;t<528;t+=256) sw[t]=wfc[t];
  __syncthreads();
  int e=blockIdx.x*256+threadIdx.x; if(e>=E) return;
  float h[16]; mlp16(emb[e], sw, h);
  float4* H4=(float4*)(H+(size_t)e*16);
  #pragma unroll
  for(int q=0;q<4;++q) H4[q]=make_float4(h[4*q],h[4*q+1],h[4*q+2],h[4*q+3]);
}

__global__ __launch_bounds__(256) void hb_k(const float* __restrict__ emb,
    const float* __restrict__ wfc, const int* __restrict__ i0,
    const int* __restrict__ i1, const int* __restrict__ i2,
    float* __restrict__ HB){
  __shared__ float sw[528];
  for(int t=threadIdx.x;t<528;t+=256) sw[t]=wfc[t];
  __syncthreads();
  int t=blockIdx.x*256+threadIdx.x; if(t>=3*N_BONDS) return;
  const int* ind = (t<N_BONDS)? i0 : (t<2*N_BONDS? i1 : i2);
  int ie = ind[t%N_BONDS];
  float h[16]; mlp16(emb[ie], sw, h);
  float4* H4=(float4*)(HB+(size_t)t*16);
  #pragma unroll
  for(int q=0;q<4;++q) H4[q]=make_float4(h[4*q],h[4*q+1],h[4*q+2],h[4*q+3]);
}

// =====================================================================
// C[e x N] = 0.25 * A[idx(e) x 16] * B[16 x N]  (edge1 weights only)
// =====================================================================
__global__ __launch_bounds__(256) void gemm16_k(const float* __restrict__ A,
    const float* __restrict__ B, float* __restrict__ C, int Eloc, int N,
    const int* __restrict__ idx){
  __shared__ float As[64][16];
  int tid=threadIdx.x;
  int et=blockIdx.x, ct=blockIdx.y;
  for(int t=tid;t<64*16;t+=256){
    int r=t/16, i=t%16;
    int e=et*64+r;
    int ea=(e<Eloc)? (idx? idx[e]:e) : -1;
    As[r][i]=(ea>=0)? A[(size_t)ea*16+i] : 0.f;
  }
  __syncthreads();
  int col=ct*64+(tid&63);
  int eq=tid>>6;
  bool colok = col<N;
  float Breg[16];
  #pragma unroll
  for(int i=0;i<16;++i) Breg[i]= colok? B[(size_t)i*N+col]*0.25f : 0.f;
  #pragma unroll 4
  for(int es=0;es<16;++es){
    int e=et*64+eq*16+es;
    if (e>=Eloc) break;
    float acc=0.f;
    #pragma unroll
    for(int i=0;i<16;++i) acc+=As[eq*16+es][i]*Breg[i];
    if (colok) C[(size_t)e*N+col]=acc;
  }
}

// =====================================================================
// Edge conv 1 GATHER: one thread per node, CSR-ordered weights.
// =====================================================================
__global__ __launch_bounds__(256) void edge1g_k(const float* __restrict__ x1,
    const float* __restrict__ sh, const float* __restrict__ ww1,
    const int* __restrict__ esrc, const int* __restrict__ sorted,
    const int* __restrict__ rowptr, const float* __restrict__ nnb,
    float* __restrict__ xout){
  int n=blockIdx.x*256+threadIdx.x; if(n>=N_NODES) return;
  float inv = rsqrtf(nnb[0]);
  const float c = 0.70710678f*inv;
  float acc[72];
  #pragma unroll
  for(int t=0;t<72;++t) acc[t]=0.f;
  int r0=rowptr[n], r1=rowptr[n+1];
  for(int r=r0;r<r1;++r){
    int e=sorted[r];
    int src=esrc[e];
    float a0=x1[2*src], a1=x1[2*src+1];
    const float4* wr4=(const float4*)(ww1+(size_t)r*48);
    float wr[48];
    #pragma unroll
    for(int q=0;q<12;++q){ float4 v=wr4[q]; wr[4*q]=v.x; wr[4*q+1]=v.y; wr[4*q+2]=v.z; wr[4*q+3]=v.w; }
    float b[9];
    #pragma unroll
    for(int j=0;j<9;++j) b[j]=sh[(size_t)e*9+j];
    #pragma unroll
    for(int w8=0;w8<8;++w8){
      float s0=wr[w8]*a0+wr[8+w8]*a1;
      acc[w8]+=s0*b[0];
      float s1=wr[16+w8]*a0+wr[24+w8]*a1;
      #pragma unroll
      for(int j=0;j<3;++j) acc[8+w8*3+j]+=s1*b[1+j];
      float s2=wr[32+w8]*a0+wr[40+w8]*a1;
      #pragma unroll
      for(int j=0;j<5;++j) acc[32+w8*5+j]+=s2*b[4+j];
    }
  }
  float* o=xout+(size_t)n*72;
  #pragma unroll
  for(int t=0;t<72;++t) o[t]=acc[t]*c;
}

// =====================================================================
// Block-diagonal linear (8ch per slice), /sqrt(8), optional tanh
// =====================================================================
template<int L>
__device__ __forceinline__ void diag_block(float* Xs, const float* __restrict__ w, bool dotanh){
  constexpr int D=2*L+1;
  const float r8=0.35355339f;
  float in[8*D];
  #pragma unroll
  for(int t=0;t<8*D;++t) in[t]=Xs[t];
  #pragma unroll
  for(int v=0;v<8;++v){
    #pragma unroll
    for(int i=0;i<D;++i){
      float acc=0.f;
      #pragma unroll
      for(int u=0;u<8;++u) acc+=in[u*D+i]*w[u*8+v];
      acc*=r8;
      Xs[v*D+i]= dotanh? tanhf(acc):acc;
    }
  }
}

__global__ __launch_bounds__(256) void lin2_k(float* __restrict__ x, const float* __restrict__ w){
  int n=blockIdx.x*256+threadIdx.x; if(n>=N_NODES) return;
  float* X=x+(size_t)n*72;
  diag_block<0>(X,    w,     true);
  diag_block<1>(X+8,  w+64,  false);
  diag_block<2>(X+32, w+128, false);
}

__global__ __launch_bounds__(256) void lin3_k(float* __restrict__ x, const float* __restrict__ w){
  int n=blockIdx.x*256+threadIdx.x; if(n>=N_NODES) return;
  float* X=x+(size_t)n*144;
  diag_block<0>(X,     w,     true);
  diag_block<0>(X+8,   w+64,  true);
  diag_block<1>(X+16,  w+128, false);
  diag_block<1>(X+40,  w+192, false);
  diag_block<2>(X+64,  w+256, false);
  diag_block<2>(X+104, w+320, false);
}

// =====================================================================
// TP path accumulate
// =====================================================================
template<int L1,int L2,int LO,int BO,int SLOT>
__device__ __forceinline__ void tp_acc(const float* Au, const float* b,
    const float* __restrict__ cg, float wv, float* acc){
  constexpr int D1=2*L1+1, D2=2*L2+1, DN=2*LO+1;
  const float* C = cg + ((L1*3+L2)*3+LO)*125;
  float P[DN];
  #pragma unroll
  for(int k=0;k<DN;++k) P[k]=0.f;
  #pragma unroll
  for(int i=0;i<D1;++i){
    float av=Au[i];
    #pragma unroll
    for(int j=0;j<D2;++j){
      float ab=av*b[BO+j];
      #pragma unroll
      for(int k=0;k<DN;++k){
        float cv=C[(i*D2+j)*DN+k];
        if(cv!=0.f) P[k]+=ab*cv;
      }
    }
  }
  #pragma unroll
  for(int k=0;k<DN;++k) acc[SLOT+k]+=wv*P[k];
}

// weight-dot from LDS-resident table + TP path, wv consumed immediately
template<int L1,int L2,int LO,int BO,int WB,int SLOT>
__device__ __forceinline__ void e2l_path(const float* Au, const float* b,
    const float* __restrict__ cg, const float* h,
    const float* Wl, int lane, float* acc){
  float s=0.f;
  #pragma unroll
  for(int i=0;i<16;++i) s += h[i]*Wl[i*960 + WB + lane];
  tp_acc<L1,L2,LO,BO,SLOT>(Au,b,cg,s*0.25f,acc);
}

__device__ __forceinline__ void e2_finish(float* acc, float inv, float* __restrict__ o){
  int lane=threadIdx.x&63;
  int w=lane&7;
  #pragma unroll
  for(int t=0;t<18;++t){
    acc[t]+=__shfl_xor(acc[t],8,64);
    acc[t]+=__shfl_xor(acc[t],16,64);
    acc[t]+=__shfl_xor(acc[t],32,64);
  }
  if (lane<8){
    float f0 =rsqrtf(24.f)*inv;
    float f1e=rsqrtf(16.f)*inv;
    float f1o=rsqrtf(32.f)*inv;
    float f2e=rsqrtf(32.f)*inv;
    float f2o=rsqrtf(16.f)*inv;
    o[0+w]=acc[0]*f0;
    o[8+w]=0.f;
    #pragma unroll
    for(int k=0;k<3;++k) o[16+w*3+k]=acc[2+k]*f1e;
    #pragma unroll
    for(int k=0;k<3;++k) o[40+w*3+k]=acc[5+k]*f1o;
    #pragma unroll
    for(int k=0;k<5;++k) o[64+w*5+k]=acc[8+k]*f2e;
    #pragma unroll
    for(int k=0;k<5;++k) o[104+w*5+k]=acc[13+k]*f2o;
  }
}

// =====================================================================
// Edge conv 2 FUSED + LDS-cached W2 (15360 f32 = 60 KB, conflict-free
// [i*960+col] layout). One wave per node; h[16] hoisted per edge.
// Per-lane acc: 0e@0, (0o@1 zero), 1e@2..4, 1o@5..7, 2e@8..12, 2o@13..17
// =====================================================================
__global__ __launch_bounds__(256) void edge2l_k(const float* __restrict__ xn,
    const float* __restrict__ sh, const float* __restrict__ h2,
    const float* __restrict__ Wg, const int* __restrict__ esrc,
    const int* __restrict__ sorted, const int* __restrict__ rowptr,
    const float* __restrict__ nnb, const float* __restrict__ cg,
    float* __restrict__ xout){
  __shared__ float Wl[15360];
  for(int t=threadIdx.x;t<15360;t+=256) Wl[t]=Wg[t];
  __syncthreads();
  int wid=threadIdx.x>>6, lane=threadIdx.x&63;
  int n=blockIdx.x*4+wid; if(n>=N_NODES) return;
  int u=lane>>3;
  float inv=rsqrtf(nnb[0]);
  int r0=rowptr[n], r1=rowptr[n+1];
  float acc[18];
  #pragma unroll
  for(int t=0;t<18;++t) acc[t]=0.f;
  for(int r=r0;r<r1;++r){
    int e=__builtin_amdgcn_readfirstlane(sorted[r]);
    int src=__builtin_amdgcn_readfirstlane(esrc[e]);
    const float* hrow = h2 + (size_t)e*16;
    float h[16];
    #pragma unroll
    for(int i=0;i<16;++i) h[i]=hrow[i];
    const float* A = xn + (size_t)src*72;
    float b[9];
    #pragma unroll
    for(int j=0;j<9;++j) b[j]=sh[(size_t)e*9+j];
    float a0[1]; a0[0]=A[u];
    float a1[3];
    #pragma unroll
    for(int i=0;i<3;++i) a1[i]=A[8+u*3+i];
    float a2[5];
    #pragma unroll
    for(int i=0;i<5;++i) a2[i]=A[32+u*5+i];
    e2l_path<0,0,0,0,   0, 0>(a0,b,cg,h,Wl,lane,acc);
    e2l_path<1,1,0,1, 256, 0>(a1,b,cg,h,Wl,lane,acc);
    e2l_path<2,2,0,4, 768, 0>(a2,b,cg,h,Wl,lane,acc);
    e2l_path<1,1,1,1, 320, 2>(a1,b,cg,h,Wl,lane,acc);
    e2l_path<2,2,1,4, 832, 2>(a2,b,cg,h,Wl,lane,acc);
    e2l_path<0,1,1,1,  64, 5>(a0,b,cg,h,Wl,lane,acc);
    e2l_path<1,0,1,0, 192, 5>(a1,b,cg,h,Wl,lane,acc);
    e2l_path<1,2,1,4, 448, 5>(a1,b,cg,h,Wl,lane,acc);
    e2l_path<2,1,1,1, 640, 5>(a2,b,cg,h,Wl,lane,acc);
    e2l_path<0,2,2,4, 128, 8>(a0,b,cg,h,Wl,lane,acc);
    e2l_path<1,1,2,1, 384, 8>(a1,b,cg,h,Wl,lane,acc);
    e2l_path<2,0,2,0, 576, 8>(a2,b,cg,h,Wl,lane,acc);
    e2l_path<2,2,2,4, 896, 8>(a2,b,cg,h,Wl,lane,acc);
    e2l_path<1,2,2,4, 512,13>(a1,b,cg,h,Wl,lane,acc);
    e2l_path<2,1,2,1, 704,13>(a2,b,cg,h,Wl,lane,acc);
  }
  e2_finish(acc, inv, xout+(size_t)n*144);
}

// =====================================================================
// Irrep linear (fan=8 per slice); zero-fills unmatched output slices.
// =====================================================================
struct IrS{ short off,m,l,p; };
__device__ const IrS SL_MID2[6]={{0,8,0,1},{8,8,0,-1},{16,8,1,1},{40,8,1,-1},{64,8,2,1},{104,8,2,-1}};
__device__ const IrS SL_HH[6]={{0,4,0,1},{4,2,1,-1},{10,2,1,-1},{16,1,0,1},{17,1,1,1},{20,1,2,1}};
__device__ const IrS SL_CC[34]={{0,9,0,1},{9,6,1,-1},{27,3,2,1},{42,6,1,-1},
 {60,1,0,1},{61,1,1,1},{64,1,2,1},{69,1,0,1},{70,1,1,1},{73,1,2,1},
 {78,1,0,1},{79,1,1,1},{82,1,2,1},{87,1,0,1},{88,1,1,1},{91,1,2,1},
 {96,1,1,-1},{99,1,2,-1},{104,1,3,-1},{111,1,1,-1},{114,1,2,-1},{119,1,3,-1},
 {126,3,2,1},{141,1,1,-1},{144,1,2,-1},{149,1,3,-1},{156,1,1,-1},{159,1,2,-1},{164,1,3,-1},
 {171,1,0,1},{172,1,1,1},{175,1,2,1},{180,1,3,1},{187,1,4,1}};
__device__ const IrS SL_CH[13]={{0,6,0,1},{6,3,1,-1},{15,4,1,-1},{27,1,0,1},{28,1,1,1},{31,1,2,1},
 {36,1,0,1},{37,1,1,1},{40,1,2,1},{45,2,2,1},{55,1,1,-1},{58,1,2,-1},{63,1,3,-1}};

__device__ void lin_out(const float* __restrict__ x, bool act16, const float* __restrict__ w,
                        const IrS* so, int no, int dim,
                        void* out, size_t base, bool f32o, float scale){
  float tx[16];
  if (act16){
    #pragma unroll
    for(int i=0;i<16;++i) tx[i]=tanhf(x[i]);
  }
  for(int i=0;i<dim;++i) stout(out, base+i, 0.f, f32o);
  int woff=0;
  for(int a=0;a<6;++a){
    int la=SL_MID2[a].l, pa=SL_MID2[a].p, oa=SL_MID2[a].off;
    int d=2*la+1;
    for(int bI=0;bI<no;++bI){
      if (so[bI].l!=la || so[bI].p!=pa) continue;
      int mo=so[bI].m;
      float f = 0.35355339f*scale;
      for(int v=0;v<mo;++v){
        for(int i=0;i<d;++i){
          float acc=0.f;
          for(int u=0;u<8;++u){
            int idx=oa+u*d+i;
            float xv=(act16 && idx<16)? tx[idx] : x[idx];
            acc+=xv*w[woff+u*mo+v];
          }
          stout(out, base+so[bI].off+v*d+i, acc*f, f32o);
        }
      }
      woff+=8*mo;
    }
  }
}

// =====================================================================
// Node outputs: nH, nC, screen
// =====================================================================
__global__ __launch_bounds__(256) void node_out_k(const float* __restrict__ x,
    const float* __restrict__ wC, const float* __restrict__ wH,
    const float* __restrict__ ws1, const float* __restrict__ ws2,
    void* out, const int* __restrict__ flag){
  int n=blockIdx.x*256+threadIdx.x; if(n>=N_NODES) return;
  bool f32o = (*flag)!=0;
  const float* X = x + (size_t)n*144;
  lin_out(X,false,wH,SL_HH,6,25,   out, (size_t)n*25, f32o, 0.2f);
  lin_out(X,false,wC,SL_CC,34,196, out, 250000 + (size_t)n*196, f32o, 0.2f);
  const float r8=0.35355339f, r32=0.17677670f;
  float t0[32];
  for(int v=0;v<32;++v){
    float acc=0.f;
    #pragma unroll
    for(int u=0;u<8;++u) acc+=X[u]*ws1[u*32+v];
    t0[v]=tanhf(acc*r8);
  }
  float t2[5];
  #pragma unroll
  for(int i=0;i<5;++i){
    float acc=0.f;
    #pragma unroll
    for(int u=0;u<8;++u) acc+=X[64+u*5+i]*ws1[256+u];
    t2[i]=acc*r8;
  }
  size_t sb = 2501000 + (size_t)n*6;
  float acc=0.f;
  for(int v=0;v<32;++v) acc+=t0[v]*ws2[v];
  stout(out, sb, acc*r32, f32o);
  float w2e=ws2[32];
  #pragma unroll
  for(int i=0;i<5;++i) stout(out, sb+1+i, t2[i]*w2e, f32o);
}

// =====================================================================
// Bond TP: one wave per bond; per-path W slice (16x512, 32 KB) staged
// into block LDS [i*512+c] (conflict-free); P exchanged via shfl.
// =====================================================================
template<int L1,int L2,int LO>
__device__ __forceinline__ void bond_pathl(const float* sa,int ao,const float* sb,int bo,
    const float* __restrict__ cg, const float* h3,
    const float* Ws, float invfan, float* sF, int oo, int lane){
  constexpr int D1=2*L1+1, D2=2*L2+1, DN=2*LO+1;
  const float* C = cg + ((L1*3+L2)*3+LO)*125;
  int u=lane>>3, v=lane&7;
  float P[DN];
  #pragma unroll
  for(int k=0;k<DN;++k) P[k]=0.f;
  #pragma unroll
  for(int i=0;i<D1;++i){
    float avv=sa[ao+u*D1+i];
    #pragma unroll
    for(int j=0;j<D2;++j){
      float ab=avv*sb[bo+v*D2+j];
      #pragma unroll
      for(int k=0;k<DN;++k){
        float cv=C[(i*D2+j)*DN+k];
        if(cv!=0.f) P[k]+=ab*cv;
      }
    }
  }
  int v2=u;  // consumer role: (v2, w) = (lane>>3, lane&7)
  float acc[DN];
  #pragma unroll
  for(int k=0;k<DN;++k) acc[k]=0.f;
  #pragma unroll
  for(int u2=0;u2<8;++u2){
    float s=0.f;
    #pragma unroll
    for(int i=0;i<16;++i) s += h3[i]*Ws[i*512 + u2*64 + lane];
    float ww=s*0.25f;
    int srcl=u2*8+v2;
    #pragma unroll
    for(int k=0;k<DN;++k) acc[k]+=ww*__shfl(P[k],srcl,64);
  }
  #pragma unroll
  for(int k=0;k<DN;++k){
    acc[k]+=__shfl_xor(acc[k],8,64);
    acc[k]+=__shfl_xor(acc[k],16,64);
    acc[k]+=__shfl_xor(acc[k],32,64);
  }
  int w=lane&7;
  if (v2==0){
    #pragma unroll
    for(int k=0;k<DN;++k) sF[oo+w*DN+k]+=acc[k]*invfan;
  }
}

__global__ __launch_bounds__(256) void bond_tpl_k(const float* __restrict__ xn,
    const float* __restrict__ hb, const float* __restrict__ Wg,
    const int* __restrict__ esrc, const int* __restrict__ edst,
    const int* __restrict__ i0, const int* __restrict__ i1,
    const int* __restrict__ i2, const float* __restrict__ cg,
    float* __restrict__ F0, float* __restrict__ F1, float* __restrict__ F2){
  __shared__ float sA[4][144], sB[4][144], sF[4][144];
  __shared__ float Ws[8192];  // 16x512 slice, [i*512+c], 32 KB
  int wid=threadIdx.x>>6, lane=threadIdx.x&63;
  int gb=blockIdx.x*4+wid;
  int s=gb/N_BONDS, bi=gb-s*N_BONDS;
  const int* ind=(s==0)?i0:(s==1)?i1:i2;
  float* F=(s==0)?F0:(s==1)?F1:F2;
  int ie=ind[bi];
  int src=esrc[ie], dst=edst[ie];
  for(int t=lane;t<144;t+=64){
    sA[wid][t]=xn[(size_t)src*144+t];
    sB[wid][t]=xn[(size_t)dst*144+t];
    sF[wid][t]=0.f;
  }
  const float* hrow = hb + (size_t)gb*16;
  float h3[16];
  #pragma unroll
  for(int i=0;i<16;++i) h3[i]=hrow[i];
  const int SL_L[6]={0,0,1,1,2,2};
  const int SL_P[6]={1,-1,1,-1,1,-1};
  const int SL_O[6]={0,8,16,40,64,104};
  const float fi0=rsqrtf(384.f), fi1=rsqrtf(768.f);
  int wbase=0;
  for(int s1=0;s1<6;++s1){
    for(int s2=0;s2<6;++s2){
      for(int so=0;so<6;++so){
        int l1=SL_L[s1], l2=SL_L[s2], lo=SL_L[so];
        if (SL_P[so]!=SL_P[s1]*SL_P[s2]) continue;
        if (lo<iabs(l1-l2) || lo>l1+l2) continue;
        __syncthreads();   // previous path's Ws consumption done
        for(int t=threadIdx.x;t<8192;t+=256){
          int i=t>>9, c=t&511;
          Ws[i*512+c]=Wg[(size_t)i*30720+wbase+c];
        }
        __syncthreads();
        int code=l1*9+l2*3+lo;
        float* a=sA[wid]; float* bb=sB[wid]; float* Ff=sF[wid];
        int ao=SL_O[s1], bo=SL_O[s2], oo=SL_O[so];
        float fv = (lo==0)? fi0 : fi1;
        switch(code){
          case 0:  bond_pathl<0,0,0>(a,ao,bb,bo,cg,h3,Ws,fv,Ff,oo,lane); break;
          case 4:  bond_pathl<0,1,1>(a,ao,bb,bo,cg,h3,Ws,fv,Ff,oo,lane); break;
          case 8:  bond_pathl<0,2,2>(a,ao,bb,bo,cg,h3,Ws,fv,Ff,oo,lane); break;
          case 10: bond_pathl<1,0,1>(a,ao,bb,bo,cg,h3,Ws,fv,Ff,oo,lane); break;
          case 12: bond_pathl<1,1,0>(a,ao,bb,bo,cg,h3,Ws,fv,Ff,oo,lane); break;
          case 13: bond_pathl<1,1,1>(a,ao,bb,bo,cg,h3,Ws,fv,Ff,oo,lane); break;
          case 14: bond_pathl<1,1,2>(a,ao,bb,bo,cg,h3,Ws,fv,Ff,oo,lane); break;
          case 16: bond_pathl<1,2,1>(a,ao,bb,bo,cg,h3,Ws,fv,Ff,oo,lane); break;
          case 17: bond_pathl<1,2,2>(a,ao,bb,bo,cg,h3,Ws,fv,Ff,oo,lane); break;
          case 20: bond_pathl<2,0,2>(a,ao,bb,bo,cg,h3,Ws,fv,Ff,oo,lane); break;
          case 22: bond_pathl<2,1,1>(a,ao,bb,bo,cg,h3,Ws,fv,Ff,oo,lane); break;
          case 23: bond_pathl<2,1,2>(a,ao,bb,bo,cg,h3,Ws,fv,Ff,oo,lane); break;
          case 24: bond_pathl<2,2,0>(a,ao,bb,bo,cg,h3,Ws,fv,Ff,oo,lane); break;
          case 25: bond_pathl<2,2,1>(a,ao,bb,bo,cg,h3,Ws,fv,Ff,oo,lane); break;
          case 26: bond_pathl<2,2,2>(a,ao,bb,bo,cg,h3,Ws,fv,Ff,oo,lane); break;
        }
        wbase+=512;
      }
    }
  }
  __syncthreads();
  for(int t=lane;t<144;t+=64) F[(size_t)bi*144+t]=sF[wid][t];
}

// =====================================================================
// Bond outputs
// =====================================================================
__global__ __launch_bounds__(256) void bond_out_k(const float* __restrict__ F,
    const float* __restrict__ wlin, int tbl, void* out, size_t baseE,
    const float* __restrict__ wg1, const float* __restrict__ wg2,
    size_t baseG, const int* __restrict__ flag){
  int n=blockIdx.x*256+threadIdx.x; if(n>=N_BONDS) return;
  bool f32o = (*flag)!=0;
  const float* X=F+(size_t)n*144;
  const IrS* so; int no; int dim;
  if(tbl==0){so=SL_HH;no=6;dim=25;}
  else if(tbl==1){so=SL_CC;no=34;dim=196;}
  else {so=SL_CH;no=13;dim=70;}
  lin_out(X,true,wlin,so,no,dim,out,baseE+(size_t)n*dim,f32o,0.2f);
  const float r8=0.35355339f, r32=0.17677670f;
  float g[32];
  for(int v=0;v<32;++v){
    float acc=0.f;
    #pragma unroll
    for(int u=0;u<8;++u) acc+=X[u]*wg1[u*32+v];
    g[v]=tanhf(acc*r8);
  }
  #pragma unroll
  for(int c=0;c<3;++c){
    float acc=0.f;
    for(int v=0;v<32;++v) acc+=g[v]*wg2[v*3+c];
    stout(out, baseG+(size_t)n*3+c, acc*r32, f32o);
  }
}

// =====================================================================
extern "C" void kernel_launch(void* const* d_in, const int* in_sizes, int n_in,
                              void* d_out, int out_size, void* d_ws, size_t ws_size,
                              hipStream_t stream){
  const int* esrc=(const int*)d_in[19];
  const int* edst=(const int*)d_in[20];
  const int* iHH =(const int*)d_in[21];
  const int* iCC =(const int*)d_in[22];
  const int* iCH =(const int*)d_in[23];
  float* ws=(float*)d_ws;
  int* flag=(int*)d_ws;

  size_t off=16;
  auto alloc=[&](size_t n){ size_t o=off; off+=(n+15)&~(size_t)15; return o; };
  size_t o_cg = alloc(27*125);
  size_t o_st[19];
  for(int i=0;i<19;++i) o_st[i]=alloc((size_t)in_sizes[i]);
  size_t o_x1  = alloc(20000);
  size_t o_xM1 = alloc(720000);
  size_t o_xM2 = alloc(1440000);
  size_t o_F0  = alloc(144000);
  size_t o_F1  = alloc(144000);
  size_t o_F2  = alloc(144000);
  size_t o_h1  = alloc((size_t)N_EDGES*16);
  size_t o_h2  = alloc((size_t)N_EDGES*16);
  size_t o_hb  = alloc((size_t)3*N_BONDS*16);
  size_t o_ww1 = alloc((size_t)N_EDGES*48);
  size_t o_cnt = alloc(10016);
  size_t o_rp  = alloc(10016);
  size_t o_pos = alloc(10016);
  size_t o_srt = alloc(N_EDGES);

  float* cg  = ws+o_cg;
  float* x1  = ws+o_x1;
  float* xM1 = ws+o_xM1;
  float* xM2 = ws+o_xM2;
  float* F0  = ws+o_F0;
  float* F1  = ws+o_F1;
  float* F2  = ws+o_F2;
  float* h1  = ws+o_h1;
  float* h2  = ws+o_h2;
  float* hb  = ws+o_hb;
  float* ww1 = ws+o_ww1;
  int* cnt   = (int*)(ws+o_cnt);
  int* rowptr= (int*)(ws+o_rp);
  int* pos   = (int*)(ws+o_pos);
  int* sorted= (int*)(ws+o_srt);

  CvtArgs ca;
  for(int i=0;i<19;++i){ ca.src[i]=d_in[i]; ca.dst[i]=ws+o_st[i]; ca.n[i]=in_sizes[i]; }
  const float* f_in   = ws+o_st[0];
  const float* sh     = ws+o_st[1];
  const float* emb    = ws+o_st[2];
  const float* nnb    = ws+o_st[3];
  const float* w_lin1 = ws+o_st[4];
  const float* w_lin2 = ws+o_st[5];
  const float* w_lin3 = ws+o_st[6];
  const float* w_linCC= ws+o_st[7];
  const float* w_linHH= ws+o_st[8];
  const float* w_linCH= ws+o_st[9];
  const float* w_linC = ws+o_st[10];
  const float* w_linH = ws+o_st[11];
  const float* w_s1   = ws+o_st[12];
  const float* w_s2   = ws+o_st[13];
  const float* w_g1   = ws+o_st[14];
  const float* w_g2   = ws+o_st[15];
  const float* w_fc1  = ws+o_st[16];
  const float* w_fc2  = ws+o_st[17];
  const float* w_fcb  = ws+o_st[18];

  detect_k<<<1,1,0,stream>>>((const unsigned short*)d_in[3], flag);
  convert_k<<<512,256,0,stream>>>(ca, flag);
  cg_init_k<<<27,128,0,stream>>>(cg);
  // CSR by destination
  hipMemsetAsync(cnt, 0, 10000*sizeof(int), stream);
  csr_count_k<<<391,256,0,stream>>>(edst, cnt);
  csr_scan_k<<<1,256,0,stream>>>(cnt, rowptr, pos);
  csr_scatter_k<<<391,256,0,stream>>>(edst, pos, sorted);

  nodeA_k<<<40,256,0,stream>>>(f_in,w_lin1,x1);
  hmlp_k<<<391,256,0,stream>>>(emb, w_fc1, h1, N_EDGES);
  hmlp_k<<<391,256,0,stream>>>(emb, w_fc2, h2, N_EDGES);
  hb_k<<<12,256,0,stream>>>(emb, w_fcb, iHH, iCC, iCH, hb);

  // edge conv 1 (small weight GEMM in CSR order + gather)
  gemm16_k<<<dim3(1563,1),256,0,stream>>>(h1, w_fc1+528, ww1, N_EDGES, 48, sorted);
  edge1g_k<<<40,256,0,stream>>>(x1,sh,ww1,esrc,sorted,rowptr,nnb,xM1);
  lin2_k<<<40,256,0,stream>>>(xM1,w_lin2);

  // edge conv 2: fused, W2 cached in LDS
  edge2l_k<<<2500,256,0,stream>>>(xM1, sh, h2, w_fc2+528,
      esrc, sorted, rowptr, nnb, cg, xM2);
  lin3_k<<<40,256,0,stream>>>(xM2,w_lin3);
  node_out_k<<<40,256,0,stream>>>(xM2,w_linC,w_linH,w_s1,w_s2,d_out,flag);

  // bonds: fused, per-path W slice in LDS
  bond_tpl_k<<<750,256,0,stream>>>(xM2, hb, w_fcb+528,
      esrc, edst, iHH, iCC, iCH, cg, F0, F1, F2);

  // outputs: 0:nH@0 1:nC@250000 2:eHH@2210000 3:eCH@2235000 4:eCC@2305000
  //          5:screen@2501000 6:gapCC@2561000 7:gapHH@2564000 8:gapCH@2567000
  bond_out_k<<<4,256,0,stream>>>(F0,w_linHH,0,d_out,2210000,w_g1,w_g2,2564000,flag);
  bond_out_k<<<4,256,0,stream>>>(F1,w_linCC,1,d_out,2305000,w_g1,w_g2,2561000,flag);
  bond_out_k<<<4,256,0,stream>>>(F2,w_linCH,2,d_out,2235000,w_g1,w_g2,2567000,flag);
}

// Round 10
// 1542.449 us; speedup vs baseline: 1.7088x; 1.7088x over previous
//
#include <hip/hip_runtime.h>
#include <hip/hip_bf16.h>

typedef __hip_bfloat16 bf16_t;

#define N_NODES 10000
#define N_EDGES 100000
#define N_BONDS 1000

__device__ __forceinline__ float bf2f(bf16_t v){ return __bfloat162float(v); }
__device__ __forceinline__ bf16_t f2bf(float v){ return __float2bfloat16(v); }
__device__ __forceinline__ int iabs(int x){ return x<0?-x:x; }

// Compile-time CG nonzero superset mask:
// (a) |m3| in {|m1|+|m2|, ||m1|-|m2||}; (b) #neg == (l1+l2+l3) mod 2.
constexpr bool cg_nz(int l1,int l2,int l3,int i,int j,int k){
  int m1=i-l1, m2=j-l2, m3=k-l3;
  int neg=(m1<0)+(m2<0)+(m3<0);
  if (((neg ^ (l1+l2+l3)) & 1)!=0) return false;
  int a1=m1<0?-m1:m1, a2=m2<0?-m2:m2, a3=m3<0?-m3:m3;
  return (a3==a1+a2)||(a3==a1-a2)||(a3==a2-a1);
}

__device__ __forceinline__ void stout(void* out, size_t idx, float v, bool f32o){
  if (f32o) ((float*)out)[idx]=v;
  else      ((bf16_t*)out)[idx]=f2bf(v);
}

// =====================================================================
// Dtype detection: num_neighbors == 10.0 always. bf16 -> u16[0]==0x4120.
// =====================================================================
__global__ void detect_k(const unsigned short* nnb_raw, int* flag){
  *flag = (nnb_raw[0]==0x4120) ? 0 : 1;
}

struct CvtArgs {
  const void* src[19];
  float* dst[19];
  int n[19];
};

__global__ __launch_bounds__(256) void convert_k(CvtArgs a, const int* flag){
  bool f32 = (*flag)!=0;
  int tid = blockIdx.x*256+threadIdx.x;
  int nth = gridDim.x*256;
  for(int t=0;t<19;++t){
    int n=a.n[t];
    float* d=a.dst[t];
    if (f32){
      const float* s=(const float*)a.src[t];
      for(int i=tid;i<n;i+=nth) d[i]=s[i];
    } else {
      const bf16_t* s=(const bf16_t*)a.src[t];
      for(int i=tid;i<n;i+=nth) d[i]=bf2f(s[i]);
    }
  }
}

// =====================================================================
// CSR build: edges sorted by destination node
// =====================================================================
__global__ __launch_bounds__(256) void csr_count_k(const int* __restrict__ edst, int* __restrict__ cnt){
  int e=blockIdx.x*256+threadIdx.x; if(e>=N_EDGES) return;
  atomicAdd(&cnt[edst[e]],1);
}

__global__ __launch_bounds__(256) void csr_scan_k(const int* __restrict__ cnt,
    int* __restrict__ rowptr, int* __restrict__ pos){
  __shared__ int ssum[256];
  int t=threadIdx.x;
  int base=t*40;
  int s=0;
  for(int i=0;i<40;++i){ int idx=base+i; s += (idx<N_NODES)? cnt[idx]:0; }
  ssum[t]=s; __syncthreads();
  if(t==0){ int run=0; for(int i=0;i<256;++i){ int v=ssum[i]; ssum[i]=run; run+=v; } }
  __syncthreads();
  int run=ssum[t];
  for(int i=0;i<40;++i){
    int idx=base+i;
    if(idx<N_NODES){ rowptr[idx]=run; pos[idx]=run; run+=cnt[idx]; }
  }
  if(t==255) rowptr[N_NODES]=run;
}

__global__ __launch_bounds__(256) void csr_scatter_k(const int* __restrict__ edst,
    int* __restrict__ pos, int* __restrict__ sorted){
  int e=blockIdx.x*256+threadIdx.x; if(e>=N_EDGES) return;
  int p=atomicAdd(&pos[edst[e]],1);
  sorted[p]=e;
}

// =====================================================================
// CG tables (device, double precision, exact replica of reference)
// =====================================================================
__device__ __forceinline__ double dfact(int n){
  const double F[11]={1.,1.,2.,6.,24.,120.,720.,5040.,40320.,362880.,3628800.};
  return F[n];
}

__device__ double cgc_d(int j1,int m1,int j2,int m2,int j3,int m3){
  if (m1+m2!=m3) return 0.0;
  double pre = sqrt((double)(2*j3+1)*dfact(j3+j1-j2)*dfact(j3-j1+j2)*dfact(j1+j2-j3)/dfact(j1+j2+j3+1));
  pre *= sqrt(dfact(j3+m3)*dfact(j3-m3)*dfact(j1-m1)*dfact(j1+m1)*dfact(j2-m2)*dfact(j2+m2));
  int k0 = max(0, max(j2-j3-m1, j1-j3+m2));
  int k1 = min(j1+j2-j3, min(j1-m1, j2+m2));
  double s=0.0;
  for(int k=k0;k<=k1;++k)
    s += ((k&1)?-1.0:1.0)/(dfact(k)*dfact(j1+j2-j3-k)*dfact(j1-m1-k)*dfact(j2+m2-k)*dfact(j3-j2+m1+k)*dfact(j3-j1-m2+k));
  return pre*s;
}

__device__ void c2r_d(int l,int a,int m,double&re,double&im){
  re=0.0; im=0.0;
  const double r2 = 0.7071067811865475244;
  int mu = a-l;
  if (mu==0){ if (m==l) re=1.0; return; }
  if (mu>0){
    if (m==l+mu) re = (mu&1)? -r2 : r2;
    else if (m==l-mu) re = r2;
  } else {
    int nu=-mu;
    if (m==l-nu) im = r2;
    else if (m==l+nu) im = (nu&1)? r2 : -r2;
  }
}

__global__ __launch_bounds__(128) void cg_init_k(float* cg){
  int b=blockIdx.x;
  int l1=b/9, l2=(b/3)%3, l3=b%3;
  if (l3 < iabs(l1-l2) || l3 > l1+l2) return;
  int n1=2*l1+1,n2=2*l2+1,n3=2*l3+1,n=n1*n2*n3;
  __shared__ double sRe[125], sIm[125];
  __shared__ int sPick;
  int t=threadIdx.x;
  if (t<n){
    int a=t/(n2*n3), bb=(t/n3)%n2, c=t%n3;
    double re=0.0, im=0.0;
    for(int m1=0;m1<n1;++m1){
      double q1r,q1i; c2r_d(l1,a,m1,q1r,q1i);
      if (q1r==0.0 && q1i==0.0) continue;
      for(int m2=0;m2<n2;++m2){
        double q2r,q2i; c2r_d(l2,bb,m2,q2r,q2i);
        if (q2r==0.0 && q2i==0.0) continue;
        int m3=(m1-l1)+(m2-l2)+l3;
        if (m3<0||m3>=n3) continue;
        double q3r,q3i; c2r_d(l3,c,m3,q3r,q3i); q3i=-q3i;
        double C = cgc_d(l1,m1-l1,l2,m2-l2,l3,m3-l3);
        if (C==0.0) continue;
        double ar = q1r*q2r - q1i*q2i;
        double ai = q1r*q2i + q1i*q2r;
        re += (ar*q3r - ai*q3i)*C;
        im += (ar*q3i + ai*q3r)*C;
      }
    }
    sRe[t]=re; sIm[t]=im;
  }
  __syncthreads();
  if (t==0){
    double s1=0.0,s2=0.0;
    for(int i=0;i<n;++i){ s1+=fabs(sRe[i]); s2+=fabs(sIm[i]); }
    sPick = (s1>=s2)?1:0;
  }
  __syncthreads();
  if (t<n) cg[b*125+t] = (float)(sPick? sRe[t] : sIm[t]);
}

// =====================================================================
// Stage A: x1 = tanh(f_in @ W(2x2) / sqrt(2))
// =====================================================================
__global__ __launch_bounds__(256) void nodeA_k(const float* __restrict__ fin,
                                               const float* __restrict__ w,
                                               float* __restrict__ x1){
  int n=blockIdx.x*256+threadIdx.x; if(n>=N_NODES) return;
  float f0=fin[2*n], f1=fin[2*n+1];
  const float r2=0.70710678f;
  x1[2*n]   = tanhf((f0*w[0]+f1*w[2])*r2);
  x1[2*n+1] = tanhf((f0*w[1]+f1*w[3])*r2);
}

// MLP [1,16,16,16] layers 0..2 of fc_apply (relu after each)
__device__ __forceinline__ void mlp16(float e, const float* w, float* h){
  float a[16];
  #pragma unroll
  for(int j=0;j<16;++j) a[j]=fmaxf(e*w[j],0.f);
  float b[16];
  #pragma unroll
  for(int j=0;j<16;++j){
    float s=0.f;
    #pragma unroll
    for(int i=0;i<16;++i) s+=a[i]*w[16+i*16+j];
    b[j]=fmaxf(s*0.25f,0.f);
  }
  #pragma unroll
  for(int j=0;j<16;++j){
    float s=0.f;
    #pragma unroll
    for(int i=0;i<16;++i) s+=b[i]*w[272+i*16+j];
    h[j]=fmaxf(s*0.25f,0.f);
  }
}

__global__ __launch_bounds__(256) void hmlp_k(const float* __restrict__ emb,
    const float* __restrict__ wfc, float* __restrict__ H, int E){
  __shared__ float sw[528];
  for(int t=threadIdx.x;t<528;t+=256) sw[t]=wfc[t];
  __syncthreads();
  int e=blockIdx.x*256+threadIdx.x; if(e>=E) return;
  float h[16]; mlp16(emb[e], sw, h);
  float4* H4=(float4*)(H+(size_t)e*16);
  #pragma unroll
  for(int q=0;q<4;++q) H4[q]=make_float4(h[4*q],h[4*q+1],h[4*q+2],h[4*q+3]);
}

__global__ __launch_bounds__(256) void hb_k(const float* __restrict__ emb,
    const float* __restrict__ wfc, const int* __restrict__ i0,
    const int* __restrict__ i1, const int* __restrict__ i2,
    float* __restrict__ HB){
  __shared__ float sw[528];
  for(int t=threadIdx.x;t<528;t+=256) sw[t]=wfc[t];
  __syncthreads();
  int t=blockIdx.x*256+threadIdx.x; if(t>=3*N_BONDS) return;
  const int* ind = (t<N_BONDS)? i0 : (t<2*N_BONDS? i1 : i2);
  int ie = ind[t%N_BONDS];
  float h[16]; mlp16(emb[ie], sw, h);
  float4* H4=(float4*)(HB+(size_t)t*16);
  #pragma unroll
  for(int q=0;q<4;++q) H4[q]=make_float4(h[4*q],h[4*q+1],h[4*q+2],h[4*q+3]);
}

// =====================================================================
// C[e x N] = 0.25 * A[idx(e) x 16] * B[16 x N]  (edge1 weights only)
// =====================================================================
__global__ __launch_bounds__(256) void gemm16_k(const float* __restrict__ A,
    const float* __restrict__ B, float* __restrict__ C, int Eloc, int N,
    const int* __restrict__ idx){
  __shared__ float As[64][16];
  int tid=threadIdx.x;
  int et=blockIdx.x, ct=blockIdx.y;
  for(int t=tid;t<64*16;t+=256){
    int r=t/16, i=t%16;
    int e=et*64+r;
    int ea=(e<Eloc)? (idx? idx[e]:e) : -1;
    As[r][i]=(ea>=0)? A[(size_t)ea*16+i] : 0.f;
  }
  __syncthreads();
  int col=ct*64+(tid&63);
  int eq=tid>>6;
  bool colok = col<N;
  float Breg[16];
  #pragma unroll
  for(int i=0;i<16;++i) Breg[i]= colok? B[(size_t)i*N+col]*0.25f : 0.f;
  #pragma unroll 4
  for(int es=0;es<16;++es){
    int e=et*64+eq*16+es;
    if (e>=Eloc) break;
    float acc=0.f;
    #pragma unroll
    for(int i=0;i<16;++i) acc+=As[eq*16+es][i]*Breg[i];
    if (colok) C[(size_t)e*N+col]=acc;
  }
}

// =====================================================================
// Edge conv 1 GATHER: one thread per node, CSR-ordered weights.
// =====================================================================
__global__ __launch_bounds__(256) void edge1g_k(const float* __restrict__ x1,
    const float* __restrict__ sh, const float* __restrict__ ww1,
    const int* __restrict__ esrc, const int* __restrict__ sorted,
    const int* __restrict__ rowptr, const float* __restrict__ nnb,
    float* __restrict__ xout){
  int n=blockIdx.x*256+threadIdx.x; if(n>=N_NODES) return;
  float inv = rsqrtf(nnb[0]);
  const float c = 0.70710678f*inv;
  float acc[72];
  #pragma unroll
  for(int t=0;t<72;++t) acc[t]=0.f;
  int r0=rowptr[n], r1=rowptr[n+1];
  for(int r=r0;r<r1;++r){
    int e=sorted[r];
    int src=esrc[e];
    float a0=x1[2*src], a1=x1[2*src+1];
    const float4* wr4=(const float4*)(ww1+(size_t)r*48);
    float wr[48];
    #pragma unroll
    for(int q=0;q<12;++q){ float4 v=wr4[q]; wr[4*q]=v.x; wr[4*q+1]=v.y; wr[4*q+2]=v.z; wr[4*q+3]=v.w; }
    float b[9];
    #pragma unroll
    for(int j=0;j<9;++j) b[j]=sh[(size_t)e*9+j];
    #pragma unroll
    for(int w8=0;w8<8;++w8){
      float s0=wr[w8]*a0+wr[8+w8]*a1;
      acc[w8]+=s0*b[0];
      float s1=wr[16+w8]*a0+wr[24+w8]*a1;
      #pragma unroll
      for(int j=0;j<3;++j) acc[8+w8*3+j]+=s1*b[1+j];
      float s2=wr[32+w8]*a0+wr[40+w8]*a1;
      #pragma unroll
      for(int j=0;j<5;++j) acc[32+w8*5+j]+=s2*b[4+j];
    }
  }
  float* o=xout+(size_t)n*72;
  #pragma unroll
  for(int t=0;t<72;++t) o[t]=acc[t]*c;
}

// =====================================================================
// Block-diagonal linear (8ch per slice), /sqrt(8), optional tanh
// =====================================================================
template<int L>
__device__ __forceinline__ void diag_block(float* Xs, const float* __restrict__ w, bool dotanh){
  constexpr int D=2*L+1;
  const float r8=0.35355339f;
  float in[8*D];
  #pragma unroll
  for(int t=0;t<8*D;++t) in[t]=Xs[t];
  #pragma unroll
  for(int v=0;v<8;++v){
    #pragma unroll
    for(int i=0;i<D;++i){
      float acc=0.f;
      #pragma unroll
      for(int u=0;u<8;++u) acc+=in[u*D+i]*w[u*8+v];
      acc*=r8;
      Xs[v*D+i]= dotanh? tanhf(acc):acc;
    }
  }
}

__global__ __launch_bounds__(256) void lin2_k(float* __restrict__ x, const float* __restrict__ w){
  int n=blockIdx.x*256+threadIdx.x; if(n>=N_NODES) return;
  float* X=x+(size_t)n*72;
  diag_block<0>(X,    w,     true);
  diag_block<1>(X+8,  w+64,  false);
  diag_block<2>(X+32, w+128, false);
}

__global__ __launch_bounds__(256) void lin3_k(float* __restrict__ x, const float* __restrict__ w){
  int n=blockIdx.x*256+threadIdx.x; if(n>=N_NODES) return;
  float* X=x+(size_t)n*144;
  diag_block<0>(X,     w,     true);
  diag_block<0>(X+8,   w+64,  true);
  diag_block<1>(X+16,  w+128, false);
  diag_block<1>(X+40,  w+192, false);
  diag_block<2>(X+64,  w+256, false);
  diag_block<2>(X+104, w+320, false);
}

// =====================================================================
// TP path accumulate — compile-time sparsity via cg_nz
// =====================================================================
template<int L1,int L2,int LO,int BO,int SLOT>
__device__ __forceinline__ void tp_acc(const float* Au, const float* b,
    const float* __restrict__ cg, float wv, float* acc){
  constexpr int D1=2*L1+1, D2=2*L2+1, DN=2*LO+1;
  const float* C = cg + ((L1*3+L2)*3+LO)*125;
  float P[DN];
  #pragma unroll
  for(int k=0;k<DN;++k) P[k]=0.f;
  #pragma unroll
  for(int i=0;i<D1;++i){
    float av=Au[i];
    #pragma unroll
    for(int j=0;j<D2;++j){
      #pragma unroll
      for(int k=0;k<DN;++k){
        if (cg_nz(L1,L2,LO,i,j,k)){
          float cv=C[(i*D2+j)*DN+k];
          P[k]+=av*(cv*b[BO+j]);
        }
      }
    }
  }
  #pragma unroll
  for(int k=0;k<DN;++k) acc[SLOT+k]+=wv*P[k];
}

// weight-dot from LDS-resident table + TP path, wv consumed immediately
template<int L1,int L2,int LO,int BO,int WB,int SLOT>
__device__ __forceinline__ void e2l_path(const float* Au, const float* b,
    const float* __restrict__ cg, const float* h,
    const float* Wl, int lane, float* acc){
  float s=0.f;
  #pragma unroll
  for(int i=0;i<16;++i) s += h[i]*Wl[i*960 + WB + lane];
  tp_acc<L1,L2,LO,BO,SLOT>(Au,b,cg,s*0.25f,acc);
}

__device__ __forceinline__ void e2_finish(float* acc, float inv, float* __restrict__ o){
  int lane=threadIdx.x&63;
  int w=lane&7;
  #pragma unroll
  for(int t=0;t<18;++t){
    acc[t]+=__shfl_xor(acc[t],8,64);
    acc[t]+=__shfl_xor(acc[t],16,64);
    acc[t]+=__shfl_xor(acc[t],32,64);
  }
  if (lane<8){
    float f0 =rsqrtf(24.f)*inv;
    float f1e=rsqrtf(16.f)*inv;
    float f1o=rsqrtf(32.f)*inv;
    float f2e=rsqrtf(32.f)*inv;
    float f2o=rsqrtf(16.f)*inv;
    o[0+w]=acc[0]*f0;
    o[8+w]=0.f;
    #pragma unroll
    for(int k=0;k<3;++k) o[16+w*3+k]=acc[2+k]*f1e;
    #pragma unroll
    for(int k=0;k<3;++k) o[40+w*3+k]=acc[5+k]*f1o;
    #pragma unroll
    for(int k=0;k<5;++k) o[64+w*5+k]=acc[8+k]*f2e;
    #pragma unroll
    for(int k=0;k<5;++k) o[104+w*5+k]=acc[13+k]*f2o;
  }
}

// =====================================================================
// Edge conv 2 FUSED + LDS-cached W2 (60 KB, [i*960+col] layout).
// One wave per node; h[16] hoisted per edge. CG compile-time sparse.
// =====================================================================
__global__ __launch_bounds__(256) void edge2l_k(const float* __restrict__ xn,
    const float* __restrict__ sh, const float* __restrict__ h2,
    const float* __restrict__ Wg, const int* __restrict__ esrc,
    const int* __restrict__ sorted, const int* __restrict__ rowptr,
    const float* __restrict__ nnb, const float* __restrict__ cg,
    float* __restrict__ xout){
  __shared__ float Wl[15360];
  for(int t=threadIdx.x;t<15360;t+=256) Wl[t]=Wg[t];
  __syncthreads();
  int wid=threadIdx.x>>6, lane=threadIdx.x&63;
  int n=blockIdx.x*4+wid; if(n>=N_NODES) return;
  int u=lane>>3;
  float inv=rsqrtf(nnb[0]);
  int r0=rowptr[n], r1=rowptr[n+1];
  float acc[18];
  #pragma unroll
  for(int t=0;t<18;++t) acc[t]=0.f;
  for(int r=r0;r<r1;++r){
    int e=__builtin_amdgcn_readfirstlane(sorted[r]);
    int src=__builtin_amdgcn_readfirstlane(esrc[e]);
    const float* hrow = h2 + (size_t)e*16;
    float h[16];
    #pragma unroll
    for(int i=0;i<16;++i) h[i]=hrow[i];
    const float* A = xn + (size_t)src*72;
    float b[9];
    #pragma unroll
    for(int j=0;j<9;++j) b[j]=sh[(size_t)e*9+j];
    float a0[1]; a0[0]=A[u];
    float a1[3];
    #pragma unroll
    for(int i=0;i<3;++i) a1[i]=A[8+u*3+i];
    float a2[5];
    #pragma unroll
    for(int i=0;i<5;++i) a2[i]=A[32+u*5+i];
    e2l_path<0,0,0,0,   0, 0>(a0,b,cg,h,Wl,lane,acc);
    e2l_path<1,1,0,1, 256, 0>(a1,b,cg,h,Wl,lane,acc);
    e2l_path<2,2,0,4, 768, 0>(a2,b,cg,h,Wl,lane,acc);
    e2l_path<1,1,1,1, 320, 2>(a1,b,cg,h,Wl,lane,acc);
    e2l_path<2,2,1,4, 832, 2>(a2,b,cg,h,Wl,lane,acc);
    e2l_path<0,1,1,1,  64, 5>(a0,b,cg,h,Wl,lane,acc);
    e2l_path<1,0,1,0, 192, 5>(a1,b,cg,h,Wl,lane,acc);
    e2l_path<1,2,1,4, 448, 5>(a1,b,cg,h,Wl,lane,acc);
    e2l_path<2,1,1,1, 640, 5>(a2,b,cg,h,Wl,lane,acc);
    e2l_path<0,2,2,4, 128, 8>(a0,b,cg,h,Wl,lane,acc);
    e2l_path<1,1,2,1, 384, 8>(a1,b,cg,h,Wl,lane,acc);
    e2l_path<2,0,2,0, 576, 8>(a2,b,cg,h,Wl,lane,acc);
    e2l_path<2,2,2,4, 896, 8>(a2,b,cg,h,Wl,lane,acc);
    e2l_path<1,2,2,4, 512,13>(a1,b,cg,h,Wl,lane,acc);
    e2l_path<2,1,2,1, 704,13>(a2,b,cg,h,Wl,lane,acc);
  }
  e2_finish(acc, inv, xout+(size_t)n*144);
}

// =====================================================================
// Irrep linear (fan=8 per slice); zero-fills unmatched output slices.
// =====================================================================
struct IrS{ short off,m,l,p; };
__device__ const IrS SL_MID2[6]={{0,8,0,1},{8,8,0,-1},{16,8,1,1},{40,8,1,-1},{64,8,2,1},{104,8,2,-1}};
__device__ const IrS SL_HH[6]={{0,4,0,1},{4,2,1,-1},{10,2,1,-1},{16,1,0,1},{17,1,1,1},{20,1,2,1}};
__device__ const IrS SL_CC[34]={{0,9,0,1},{9,6,1,-1},{27,3,2,1},{42,6,1,-1},
 {60,1,0,1},{61,1,1,1},{64,1,2,1},{69,1,0,1},{70,1,1,1},{73,1,2,1},
 {78,1,0,1},{79,1,1,1},{82,1,2,1},{87,1,0,1},{88,1,1,1},{91,1,2,1},
 {96,1,1,-1},{99,1,2,-1},{104,1,3,-1},{111,1,1,-1},{114,1,2,-1},{119,1,3,-1},
 {126,3,2,1},{141,1,1,-1},{144,1,2,-1},{149,1,3,-1},{156,1,1,-1},{159,1,2,-1},{164,1,3,-1},
 {171,1,0,1},{172,1,1,1},{175,1,2,1},{180,1,3,1},{187,1,4,1}};
__device__ const IrS SL_CH[13]={{0,6,0,1},{6,3,1,-1},{15,4,1,-1},{27,1,0,1},{28,1,1,1},{31,1,2,1},
 {36,1,0,1},{37,1,1,1},{40,1,2,1},{45,2,2,1},{55,1,1,-1},{58,1,2,-1},{63,1,3,-1}};

__device__ void lin_out(const float* __restrict__ x, bool act16, const float* __restrict__ w,
                        const IrS* so, int no, int dim,
                        void* out, size_t base, bool f32o, float scale){
  float tx[16];
  if (act16){
    #pragma unroll
    for(int i=0;i<16;++i) tx[i]=tanhf(x[i]);
  }
  for(int i=0;i<dim;++i) stout(out, base+i, 0.f, f32o);
  int woff=0;
  for(int a=0;a<6;++a){
    int la=SL_MID2[a].l, pa=SL_MID2[a].p, oa=SL_MID2[a].off;
    int d=2*la+1;
    for(int bI=0;bI<no;++bI){
      if (so[bI].l!=la || so[bI].p!=pa) continue;
      int mo=so[bI].m;
      float f = 0.35355339f*scale;
      for(int v=0;v<mo;++v){
        for(int i=0;i<d;++i){
          float acc=0.f;
          for(int u=0;u<8;++u){
            int idx=oa+u*d+i;
            float xv=(act16 && idx<16)? tx[idx] : x[idx];
            acc+=xv*w[woff+u*mo+v];
          }
          stout(out, base+so[bI].off+v*d+i, acc*f, f32o);
        }
      }
      woff+=8*mo;
    }
  }
}

// =====================================================================
// Node outputs: nH, nC, screen
// =====================================================================
__global__ __launch_bounds__(256) void node_out_k(const float* __restrict__ x,
    const float* __restrict__ wC, const float* __restrict__ wH,
    const float* __restrict__ ws1, const float* __restrict__ ws2,
    void* out, const int* __restrict__ flag){
  int n=blockIdx.x*256+threadIdx.x; if(n>=N_NODES) return;
  bool f32o = (*flag)!=0;
  const float* X = x + (size_t)n*144;
  lin_out(X,false,wH,SL_HH,6,25,   out, (size_t)n*25, f32o, 0.2f);
  lin_out(X,false,wC,SL_CC,34,196, out, 250000 + (size_t)n*196, f32o, 0.2f);
  const float r8=0.35355339f, r32=0.17677670f;
  float t0[32];
  for(int v=0;v<32;++v){
    float acc=0.f;
    #pragma unroll
    for(int u=0;u<8;++u) acc+=X[u]*ws1[u*32+v];
    t0[v]=tanhf(acc*r8);
  }
  float t2[5];
  #pragma unroll
  for(int i=0;i<5;++i){
    float acc=0.f;
    #pragma unroll
    for(int u=0;u<8;++u) acc+=X[64+u*5+i]*ws1[256+u];
    t2[i]=acc*r8;
  }
  size_t sb = 2501000 + (size_t)n*6;
  float acc=0.f;
  for(int v=0;v<32;++v) acc+=t0[v]*ws2[v];
  stout(out, sb, acc*r32, f32o);
  float w2e=ws2[32];
  #pragma unroll
  for(int i=0;i<5;++i) stout(out, sb+1+i, t2[i]*w2e, f32o);
}

// =====================================================================
// Bond TP: one wave per bond; per-path W slice (16x512, 32 KB) staged
// into block LDS; P exchanged via shfl; CG compile-time sparse.
// =====================================================================
template<int L1,int L2,int LO>
__device__ __forceinline__ void bond_pathl(const float* sa,int ao,const float* sb,int bo,
    const float* __restrict__ cg, const float* h3,
    const float* Ws, float invfan, float* sF, int oo, int lane){
  constexpr int D1=2*L1+1, D2=2*L2+1, DN=2*LO+1;
  const float* C = cg + ((L1*3+L2)*3+LO)*125;
  int u=lane>>3, v=lane&7;
  float P[DN];
  #pragma unroll
  for(int k=0;k<DN;++k) P[k]=0.f;
  #pragma unroll
  for(int i=0;i<D1;++i){
    float avv=sa[ao+u*D1+i];
    #pragma unroll
    for(int j=0;j<D2;++j){
      #pragma unroll
      for(int k=0;k<DN;++k){
        if (cg_nz(L1,L2,LO,i,j,k)){
          float cv=C[(i*D2+j)*DN+k];
          P[k]+=(avv*sb[bo+v*D2+j])*cv;
        }
      }
    }
  }
  int v2=u;  // consumer role: (v2, w) = (lane>>3, lane&7)
  float acc[DN];
  #pragma unroll
  for(int k=0;k<DN;++k) acc[k]=0.f;
  #pragma unroll
  for(int u2=0;u2<8;++u2){
    float s=0.f;
    #pragma unroll
    for(int i=0;i<16;++i) s += h3[i]*Ws[i*512 + u2*64 + lane];
    float ww=s*0.25f;
    int srcl=u2*8+v2;
    #pragma unroll
    for(int k=0;k<DN;++k) acc[k]+=ww*__shfl(P[k],srcl,64);
  }
  #pragma unroll
  for(int k=0;k<DN;++k){
    acc[k]+=__shfl_xor(acc[k],8,64);
    acc[k]+=__shfl_xor(acc[k],16,64);
    acc[k]+=__shfl_xor(acc[k],32,64);
  }
  int w=lane&7;
  if (v2==0){
    #pragma unroll
    for(int k=0;k<DN;++k) sF[oo+w*DN+k]+=acc[k]*invfan;
  }
}

__global__ __launch_bounds__(256) void bond_tpl_k(const float* __restrict__ xn,
    const float* __restrict__ hb, const float* __restrict__ Wg,
    const int* __restrict__ esrc, const int* __restrict__ edst,
    const int* __restrict__ i0, const int* __restrict__ i1,
    const int* __restrict__ i2, const float* __restrict__ cg,
    float* __restrict__ F0, float* __restrict__ F1, float* __restrict__ F2){
  __shared__ float sA[4][144], sB[4][144], sF[4][144];
  __shared__ float Ws[8192];  // 16x512 slice, [i*512+c], 32 KB
  int wid=threadIdx.x>>6, lane=threadIdx.x&63;
  int gb=blockIdx.x*4+wid;
  int s=gb/N_BONDS, bi=gb-s*N_BONDS;
  const int* ind=(s==0)?i0:(s==1)?i1:i2;
  float* F=(s==0)?F0:(s==1)?F1:F2;
  int ie=ind[bi];
  int src=esrc[ie], dst=edst[ie];
  for(int t=lane;t<144;t+=64){
    sA[wid][t]=xn[(size_t)src*144+t];
    sB[wid][t]=xn[(size_t)dst*144+t];
    sF[wid][t]=0.f;
  }
  const float* hrow = hb + (size_t)gb*16;
  float h3[16];
  #pragma unroll
  for(int i=0;i<16;++i) h3[i]=hrow[i];
  const int SL_L[6]={0,0,1,1,2,2};
  const int SL_P[6]={1,-1,1,-1,1,-1};
  const int SL_O[6]={0,8,16,40,64,104};
  const float fi0=rsqrtf(384.f), fi1=rsqrtf(768.f);
  int wbase=0;
  for(int s1=0;s1<6;++s1){
    for(int s2=0;s2<6;++s2){
      for(int so=0;so<6;++so){
        int l1=SL_L[s1], l2=SL_L[s2], lo=SL_L[so];
        if (SL_P[so]!=SL_P[s1]*SL_P[s2]) continue;
        if (lo<iabs(l1-l2) || lo>l1+l2) continue;
        __syncthreads();   // previous path's Ws consumption done
        for(int t=threadIdx.x;t<8192;t+=256){
          int i=t>>9, c=t&511;
          Ws[i*512+c]=Wg[(size_t)i*30720+wbase+c];
        }
        __syncthreads();
        int code=l1*9+l2*3+lo;
        float* a=sA[wid]; float* bb=sB[wid]; float* Ff=sF[wid];
        int ao=SL_O[s1], bo=SL_O[s2], oo=SL_O[so];
        float fv = (lo==0)? fi0 : fi1;
        switch(code){
          case 0:  bond_pathl<0,0,0>(a,ao,bb,bo,cg,h3,Ws,fv,Ff,oo,lane); break;
          case 4:  bond_pathl<0,1,1>(a,ao,bb,bo,cg,h3,Ws,fv,Ff,oo,lane); break;
          case 8:  bond_pathl<0,2,2>(a,ao,bb,bo,cg,h3,Ws,fv,Ff,oo,lane); break;
          case 10: bond_pathl<1,0,1>(a,ao,bb,bo,cg,h3,Ws,fv,Ff,oo,lane); break;
          case 12: bond_pathl<1,1,0>(a,ao,bb,bo,cg,h3,Ws,fv,Ff,oo,lane); break;
          case 13: bond_pathl<1,1,1>(a,ao,bb,bo,cg,h3,Ws,fv,Ff,oo,lane); break;
          case 14: bond_pathl<1,1,2>(a,ao,bb,bo,cg,h3,Ws,fv,Ff,oo,lane); break;
          case 16: bond_pathl<1,2,1>(a,ao,bb,bo,cg,h3,Ws,fv,Ff,oo,lane); break;
          case 17: bond_pathl<1,2,2>(a,ao,bb,bo,cg,h3,Ws,fv,Ff,oo,lane); break;
          case 20: bond_pathl<2,0,2>(a,ao,bb,bo,cg,h3,Ws,fv,Ff,oo,lane); break;
          case 22: bond_pathl<2,1,1>(a,ao,bb,bo,cg,h3,Ws,fv,Ff,oo,lane); break;
          case 23: bond_pathl<2,1,2>(a,ao,bb,bo,cg,h3,Ws,fv,Ff,oo,lane); break;
          case 24: bond_pathl<2,2,0>(a,ao,bb,bo,cg,h3,Ws,fv,Ff,oo,lane); break;
          case 25: bond_pathl<2,2,1>(a,ao,bb,bo,cg,h3,Ws,fv,Ff,oo,lane); break;
          case 26: bond_pathl<2,2,2>(a,ao,bb,bo,cg,h3,Ws,fv,Ff,oo,lane); break;
        }
        wbase+=512;
      }
    }
  }
  __syncthreads();
  for(int t=lane;t<144;t+=64) F[(size_t)bi*144+t]=sF[wid][t];
}

// =====================================================================
// Bond outputs
// =====================================================================
__global__ __launch_bounds__(256) void bond_out_k(const float* __restrict__ F,
    const float* __restrict__ wlin, int tbl, void* out, size_t baseE,
    const float* __restrict__ wg1, const float* __restrict__ wg2,
    size_t baseG, const int* __restrict__ flag){
  int n=blockIdx.x*256+threadIdx.x; if(n>=N_BONDS) return;
  bool f32o = (*flag)!=0;
  const float* X=F+(size_t)n*144;
  const IrS* so; int no; int dim;
  if(tbl==0){so=SL_HH;no=6;dim=25;}
  else if(tbl==1){so=SL_CC;no=34;dim=196;}
  else {so=SL_CH;no=13;dim=70;}
  lin_out(X,true,wlin,so,no,dim,out,baseE+(size_t)n*dim,f32o,0.2f);
  const float r8=0.35355339f, r32=0.17677670f;
  float g[32];
  for(int v=0;v<32;++v){
    float acc=0.f;
    #pragma unroll
    for(int u=0;u<8;++u) acc+=X[u]*wg1[u*32+v];
    g[v]=tanhf(acc*r8);
  }
  #pragma unroll
  for(int c=0;c<3;++c){
    float acc=0.f;
    for(int v=0;v<32;++v) acc+=g[v]*wg2[v*3+c];
    stout(out, baseG+(size_t)n*3+c, acc*r32, f32o);
  }
}

// =====================================================================
extern "C" void kernel_launch(void* const* d_in, const int* in_sizes, int n_in,
                              void* d_out, int out_size, void* d_ws, size_t ws_size,
                              hipStream_t stream){
  const int* esrc=(const int*)d_in[19];
  const int* edst=(const int*)d_in[20];
  const int* iHH =(const int*)d_in[21];
  const int* iCC =(const int*)d_in[22];
  const int* iCH =(const int*)d_in[23];
  float* ws=(float*)d_ws;
  int* flag=(int*)d_ws;

  size_t off=16;
  auto alloc=[&](size_t n){ size_t o=off; off+=(n+15)&~(size_t)15; return o; };
  size_t o_cg = alloc(27*125);
  size_t o_st[19];
  for(int i=0;i<19;++i) o_st[i]=alloc((size_t)in_sizes[i]);
  size_t o_x1  = alloc(20000);
  size_t o_xM1 = alloc(720000);
  size_t o_xM2 = alloc(1440000);
  size_t o_F0  = alloc(144000);
  size_t o_F1  = alloc(144000);
  size_t o_F2  = alloc(144000);
  size_t o_h1  = alloc((size_t)N_EDGES*16);
  size_t o_h2  = alloc((size_t)N_EDGES*16);
  size_t o_hb  = alloc((size_t)3*N_BONDS*16);
  size_t o_ww1 = alloc((size_t)N_EDGES*48);
  size_t o_cnt = alloc(10016);
  size_t o_rp  = alloc(10016);
  size_t o_pos = alloc(10016);
  size_t o_srt = alloc(N_EDGES);

  float* cg  = ws+o_cg;
  float* x1  = ws+o_x1;
  float* xM1 = ws+o_xM1;
  float* xM2 = ws+o_xM2;
  float* F0  = ws+o_F0;
  float* F1  = ws+o_F1;
  float* F2  = ws+o_F2;
  float* h1  = ws+o_h1;
  float* h2  = ws+o_h2;
  float* hb  = ws+o_hb;
  float* ww1 = ws+o_ww1;
  int* cnt   = (int*)(ws+o_cnt);
  int* rowptr= (int*)(ws+o_rp);
  int* pos   = (int*)(ws+o_pos);
  int* sorted= (int*)(ws+o_srt);

  CvtArgs ca;
  for(int i=0;i<19;++i){ ca.src[i]=d_in[i]; ca.dst[i]=ws+o_st[i]; ca.n[i]=in_sizes[i]; }
  const float* f_in   = ws+o_st[0];
  const float* sh     = ws+o_st[1];
  const float* emb    = ws+o_st[2];
  const float* nnb    = ws+o_st[3];
  const float* w_lin1 = ws+o_st[4];
  const float* w_lin2 = ws+o_st[5];
  const float* w_lin3 = ws+o_st[6];
  const float* w_linCC= ws+o_st[7];
  const float* w_linHH= ws+o_st[8];
  const float* w_linCH= ws+o_st[9];
  const float* w_linC = ws+o_st[10];
  const float* w_linH = ws+o_st[11];
  const float* w_s1   = ws+o_st[12];
  const float* w_s2   = ws+o_st[13];
  const float* w_g1   = ws+o_st[14];
  const float* w_g2   = ws+o_st[15];
  const float* w_fc1  = ws+o_st[16];
  const float* w_fc2  = ws+o_st[17];
  const float* w_fcb  = ws+o_st[18];

  detect_k<<<1,1,0,stream>>>((const unsigned short*)d_in[3], flag);
  convert_k<<<512,256,0,stream>>>(ca, flag);
  cg_init_k<<<27,128,0,stream>>>(cg);
  // CSR by destination
  hipMemsetAsync(cnt, 0, 10000*sizeof(int), stream);
  csr_count_k<<<391,256,0,stream>>>(edst, cnt);
  csr_scan_k<<<1,256,0,stream>>>(cnt, rowptr, pos);
  csr_scatter_k<<<391,256,0,stream>>>(edst, pos, sorted);

  nodeA_k<<<40,256,0,stream>>>(f_in,w_lin1,x1);
  hmlp_k<<<391,256,0,stream>>>(emb, w_fc1, h1, N_EDGES);
  hmlp_k<<<391,256,0,stream>>>(emb, w_fc2, h2, N_EDGES);
  hb_k<<<12,256,0,stream>>>(emb, w_fcb, iHH, iCC, iCH, hb);

  // edge conv 1 (small weight GEMM in CSR order + gather)
  gemm16_k<<<dim3(1563,1),256,0,stream>>>(h1, w_fc1+528, ww1, N_EDGES, 48, sorted);
  edge1g_k<<<40,256,0,stream>>>(x1,sh,ww1,esrc,sorted,rowptr,nnb,xM1);
  lin2_k<<<40,256,0,stream>>>(xM1,w_lin2);

  // edge conv 2: fused, W2 cached in LDS, CG compile-time sparse
  edge2l_k<<<2500,256,0,stream>>>(xM1, sh, h2, w_fc2+528,
      esrc, sorted, rowptr, nnb, cg, xM2);
  lin3_k<<<40,256,0,stream>>>(xM2,w_lin3);
  node_out_k<<<40,256,0,stream>>>(xM2,w_linC,w_linH,w_s1,w_s2,d_out,flag);

  // bonds: fused, per-path W slice in LDS, CG compile-time sparse
  bond_tpl_k<<<750,256,0,stream>>>(xM2, hb, w_fcb+528,
      esrc, edst, iHH, iCC, iCH, cg, F0, F1, F2);

  // outputs: 0:nH@0 1:nC@250000 2:eHH@2210000 3:eCH@2235000 4:eCC@2305000
  //          5:screen@2501000 6:gapCC@2561000 7:gapHH@2564000 8:gapCH@2567000
  bond_out_k<<<4,256,0,stream>>>(F0,w_linHH,0,d_out,2210000,w_g1,w_g2,2564000,flag);
  bond_out_k<<<4,256,0,stream>>>(F1,w_linCC,1,d_out,2305000,w_g1,w_g2,2561000,flag);
  bond_out_k<<<4,256,0,stream>>>(F2,w_linCH,2,d_out,2235000,w_g1,w_g2,2567000,flag);
}